// Round 14
// baseline (220.363 us; speedup 1.0000x reference)
//
#include <hip/hip_runtime.h>

static constexpr int Lc = 512;
static constexpr int Bc = 256;
static constexpr int Tc = 128;

typedef _Float16 half2_t  __attribute__((ext_vector_type(2)));
typedef __fp16   fp16x2_t __attribute__((ext_vector_type(2)));

__device__ __forceinline__ float fdot2(half2_t a, half2_t b, float c) {
  return __builtin_amdgcn_fdot2(a, b, c, false);   // v_dot2_f32_f16
}
__device__ __forceinline__ unsigned pack_h2(float a, float b) {
  union { fp16x2_t h; unsigned u; } cv;
  cv.h = __builtin_amdgcn_cvt_pkrtz(a, b);         // v_cvt_pkrtz_f16_f32
  return cv.u;
}
__device__ __forceinline__ half2_t as_h2(unsigned u) {
  union { unsigned u; half2_t h; } cv;
  cv.u = u;
  return cv.h;
}

// Meet-in-the-middle (R13 math) + BARRIER-FREE single-wave chains (R6
// machinery): each chain (fwd or bwd half of one batch) lives in ONE wave;
// the LDS p-broadcast self-syncs via the wave's own lgkmcnt — no s_barrier
// in the recurrence at all. 8 chains per 512-thread block => 2 waves/SIMD
// co-resident: one wave's LDS/dep stalls hide under the other's issue.
// Lane l owns j0=2l, j1=2l+1 with the full 128-i reduction: 128 dot2 against
// 128 packed-f16x2 E words (fully unrolled -> register/AGPR resident).
// Rescale: exact 2^-e0, e0 = exponent of element 0 via readfirstlane (SALU).
__launch_bounds__(512, 2)
__global__ void crf_llh_kernel(const float* __restrict__ emis,
                               const int* __restrict__ tags,
                               const int* __restrict__ mask,
                               const float* __restrict__ startT,
                               const float* __restrict__ endT,
                               const float* __restrict__ trans,
                               float* __restrict__ pbuf,    // [256][128]
                               float* __restrict__ qbuf,    // [256][128]
                               float* __restrict__ meta)    // [256][4]
{
  const int tid = threadIdx.x;
  const int wv  = tid >> 6;              // wave 0..7
  const int l   = tid & 63;
  const int b   = blockIdx.x * 4 + (wv & 3);
  const bool fw = (wv >> 2) == 0;        // waves 0-3 fwd, 4-7 bwd
  const int j0  = 2 * l;
  const int j1  = 2 * l + 1;

  __shared__ __align__(16) unsigned p_lds[8][2][64];   // per-wave regions

  const size_t strideT = (size_t)Bc * Tc;
  const float* emrow = emis + (size_t)b * Tc;

  if (fw) {
    // ---------- numerator (gold-path score), wave-local ----------
    float score = 0.f;   // lane 0
    {
      float v = 0.f, c = 0.f;
      for (int k = 0; k < 8; ++k) {
        const int t = l + 64 * k;
        const float mf  = (float)mask[t * Bc + b];
        const int tag_t = tags[t * Bc + b];
        float e = emis[((size_t)t * Bc + b) * Tc + tag_t] * mf;
        if (t >= 1) e += trans[tags[(t - 1) * Bc + b] * Tc + tag_t] * mf;
        v += e; c += mf;
      }
      #pragma unroll
      for (int o = 1; o < 64; o <<= 1) {
        v += __shfl_xor(v, o);
        c += __shfl_xor(c, o);
      }
      if (l == 0) {
        const int last_idx = (int)(c + 0.5f) - 1;
        score = v + startT[tags[b]] + endT[tags[last_idx * Bc + b]];
      }
    }

    // ---------- E columns j0,j1 packed along i: 128 u32 ----------
    unsigned Eu0[64], Eu1[64];
    #pragma unroll
    for (int q = 0; q < 64; ++q) {
      const float2 r0 = *(const float2*)&trans[(2 * q)     * Tc + j0];
      const float2 r1 = *(const float2*)&trans[(2 * q + 1) * Tc + j0];
      Eu0[q] = pack_h2(__expf(r0.x), __expf(r1.x));
      Eu1[q] = pack_h2(__expf(r0.y), __expf(r1.y));
    }

    // ---------- init t = 0 ----------
    const float2 em00 = *(const float2*)&emrow[j0];
    const float lpA = startT[j0] + em00.x;
    const float lpB = startT[j1] + em00.y;
    float wm = fmaxf(lpA, lpB);
    #pragma unroll
    for (int o = 1; o < 64; o <<= 1) wm = fmaxf(wm, __shfl_xor(wm, o));
    const float M0 = wm;
    float pA = __expf(lpA - M0);
    float pB = __expf(lpB - M0);
    p_lds[wv][0][l] = pack_h2(pA, pB);

    // em/mask prefetch, 3 deep (t=1,2,3); all loop prefetches in-bounds
    float2 emC = *(const float2*)&emrow[1 * strideT + j0];
    float2 emD = *(const float2*)&emrow[2 * strideT + j0];
    float2 emE = *(const float2*)&emrow[3 * strideT + j0];
    int mC = mask[1 * Bc + b], mD = mask[2 * Bc + b], mE = mask[3 * Bc + b];
    const float* emP = emrow + 4 * strideT + j0;
    const int*   mP  = mask + 4 * Bc + b;

    int Ks = 0, buf = 0;
    for (int t = 1; t <= 255; ++t) {
      uint4 pr[16];
      const uint4* pv = (const uint4*)p_lds[wv][buf];
      #pragma unroll
      for (int q = 0; q < 16; ++q) pr[q] = pv[q];

      const float eE0 = __expf(emC.x);
      const float eE1 = __expf(emC.y);

      // prefetch t+3 (<= 258 < 512, always valid)
      const float2 emN = *(const float2*)emP;
      const int    mN  = mP[0];
      emP += strideT; mP += Bc;

      float a0 = 0.f, a1 = 0.f, a2 = 0.f, a3 = 0.f;
      float c0 = 0.f, c1 = 0.f, c2 = 0.f, c3 = 0.f;
      #pragma unroll
      for (int q = 0; q < 16; ++q) {
        a0 = fdot2(as_h2(pr[q].x), as_h2(Eu0[4 * q + 0]), a0);
        c0 = fdot2(as_h2(pr[q].x), as_h2(Eu1[4 * q + 0]), c0);
        a1 = fdot2(as_h2(pr[q].y), as_h2(Eu0[4 * q + 1]), a1);
        c1 = fdot2(as_h2(pr[q].y), as_h2(Eu1[4 * q + 1]), c1);
        a2 = fdot2(as_h2(pr[q].z), as_h2(Eu0[4 * q + 2]), a2);
        c2 = fdot2(as_h2(pr[q].z), as_h2(Eu1[4 * q + 2]), c2);
        a3 = fdot2(as_h2(pr[q].w), as_h2(Eu0[4 * q + 3]), a3);
        c3 = fdot2(as_h2(pr[q].w), as_h2(Eu1[4 * q + 3]), c3);
      }
      const float s0 = (a0 + a1) + (a2 + a3);
      const float s1 = (c0 + c1) + (c2 + c3);

      float pn0 = mC ? s0 * eE0 : pA;
      float pn1 = mC ? s1 * eE1 : pB;

      const unsigned bits =
          (unsigned)__builtin_amdgcn_readfirstlane((int)__float_as_uint(pn0));
      int e0 = (int)((bits >> 23) & 0xff) - 127;
      e0 = min(max(e0, -100), 100);
      const float r = __uint_as_float((unsigned)(127 - e0) << 23);
      Ks += e0;
      pA = pn0 * r;
      pB = pn1 * r;
      p_lds[wv][buf ^ 1][l] = pack_h2(pA, pB);

      emC = emD; emD = emE; emE = emN;
      mC  = mD;  mD  = mE;  mE  = mN;
      buf ^= 1;
    }

    float2 outp; outp.x = pA; outp.y = pB;
    *(float2*)&pbuf[b * Tc + j0] = outp;
    if (l == 0) {
      meta[4 * b + 0] = score;
      meta[4 * b + 1] = M0;
      meta[4 * b + 2] = (float)Ks;
    }
  } else {
    // ---------- E rows i0=2l, i1=2l+1 packed along j: 128 u32 ----------
    unsigned Eu0[64], Eu1[64];
    #pragma unroll
    for (int q = 0; q < 64; ++q) {
      const float2 r0 = *(const float2*)&trans[(2 * l)     * Tc + 2 * q];
      const float2 r1 = *(const float2*)&trans[(2 * l + 1) * Tc + 2 * q];
      Eu0[q] = pack_h2(__expf(r0.x), __expf(r0.y));
      Eu1[q] = pack_h2(__expf(r1.x), __expf(r1.y));
    }

    // ---------- init: q_511 = exp(end); u_511 = eEm_511 .* q_511 ----------
    float qA = __expf(endT[j0]);
    float qB = __expf(endT[j1]);
    {
      const float2 em511 = *(const float2*)&emrow[511 * strideT + j0];
      p_lds[wv][0][l] = pack_h2(qA * __expf(em511.x), qB * __expf(em511.y));
    }

    // streams: m[511],m[510],m[509]; em[510],em[509],em[508]
    int mC = mask[511 * Bc + b], mD = mask[510 * Bc + b], mE = mask[509 * Bc + b];
    float2 emC = *(const float2*)&emrow[510 * strideT + j0];
    float2 emD = *(const float2*)&emrow[509 * strideT + j0];
    float2 emE = *(const float2*)&emrow[508 * strideT + j0];
    const float* emP = emrow + 507 * strideT + j0;   // em[507-k]
    const int*   mP  = mask + 508 * Bc + b;          // m[508-k]

    int Ks = 0, buf = 0;
    for (int k = 0; k < 256; ++k) {                  // t = 511 - k
      uint4 pr[16];
      const uint4* pv = (const uint4*)p_lds[wv][buf];
      #pragma unroll
      for (int q = 0; q < 16; ++q) pr[q] = pv[q];

      // prefetch (always in-bounds: em[507-k] >= em[252], m[508-k] >= m[253])
      const float2 emN = *(const float2*)emP;
      const int    mN  = mP[0];
      emP -= strideT; mP -= Bc;

      float a0 = 0.f, a1 = 0.f, a2 = 0.f, a3 = 0.f;
      float c0 = 0.f, c1 = 0.f, c2 = 0.f, c3 = 0.f;
      #pragma unroll
      for (int q = 0; q < 16; ++q) {
        a0 = fdot2(as_h2(pr[q].x), as_h2(Eu0[4 * q + 0]), a0);
        c0 = fdot2(as_h2(pr[q].x), as_h2(Eu1[4 * q + 0]), c0);
        a1 = fdot2(as_h2(pr[q].y), as_h2(Eu0[4 * q + 1]), a1);
        c1 = fdot2(as_h2(pr[q].y), as_h2(Eu1[4 * q + 1]), c1);
        a2 = fdot2(as_h2(pr[q].z), as_h2(Eu0[4 * q + 2]), a2);
        c2 = fdot2(as_h2(pr[q].z), as_h2(Eu1[4 * q + 2]), c2);
        a3 = fdot2(as_h2(pr[q].w), as_h2(Eu0[4 * q + 3]), a3);
        c3 = fdot2(as_h2(pr[q].w), as_h2(Eu1[4 * q + 3]), c3);
      }
      const float s0 = (a0 + a1) + (a2 + a3);
      const float s1 = (c0 + c1) + (c2 + c3);

      float pn0 = mC ? s0 : qA;     // q_{t-1}
      float pn1 = mC ? s1 : qB;

      const unsigned bits =
          (unsigned)__builtin_amdgcn_readfirstlane((int)__float_as_uint(pn0));
      int e0 = (int)((bits >> 23) & 0xff) - 127;
      e0 = min(max(e0, -100), 100);
      const float r = __uint_as_float((unsigned)(127 - e0) << 23);
      Ks += e0;
      qA = pn0 * r;
      qB = pn1 * r;

      // u_{t-1} = eEm_{t-1} .* q_{t-1}
      p_lds[wv][buf ^ 1][l] = pack_h2(qA * __expf(emC.x), qB * __expf(emC.y));

      emC = emD; emD = emE; emE = emN;
      mC  = mD;  mD  = mE;  mE  = mN;
      buf ^= 1;
    }

    float2 outq; outq.x = qA; outq.y = qB;
    *(float2*)&qbuf[b * Tc + j0] = outq;
    if (l == 0) meta[4 * b + 3] = (float)Ks;
  }
}

// Meet: denom_b = M0 + (Kf+Kb)*ln2 + log(p_255 . q_255); partial = score - denom.
__global__ void crf_meet(const float* __restrict__ pbuf,
                         const float* __restrict__ qbuf,
                         const float* __restrict__ meta,
                         float* __restrict__ partial)
{
  const int b = blockIdx.x;
  const int l = threadIdx.x;   // 64
  const float2 pp = *(const float2*)&pbuf[b * Tc + 2 * l];
  const float2 qq = *(const float2*)&qbuf[b * Tc + 2 * l];
  float d = pp.x * qq.x + pp.y * qq.y;
  #pragma unroll
  for (int o = 1; o < 64; o <<= 1) d += __shfl_xor(d, o);
  if (l == 0) {
    const float score = meta[4 * b + 0];
    const float M0    = meta[4 * b + 1];
    const float Ks    = meta[4 * b + 2] + meta[4 * b + 3];
    partial[b] = score - (M0 + Ks * 0.69314718055994531f + __logf(d));
  }
}

// Deterministic final reduction of 256 per-batch llh values -> scalar.
__global__ void crf_reduce(const float* __restrict__ partial, float* __restrict__ out)
{
  const int tid = threadIdx.x;  // 256 threads
  float v = partial[tid];
  #pragma unroll
  for (int o = 1; o < 64; o <<= 1) v += __shfl_xor(v, o);
  __shared__ float ws[4];
  if ((tid & 63) == 0) ws[tid >> 6] = v;
  __syncthreads();
  if (tid == 0) out[0] = (ws[0] + ws[1]) + (ws[2] + ws[3]);
}

extern "C" void kernel_launch(void* const* d_in, const int* in_sizes, int n_in,
                              void* d_out, int out_size, void* d_ws, size_t ws_size,
                              hipStream_t stream)
{
  const float* emis   = (const float*)d_in[0];
  const int*   tags   = (const int*)d_in[1];
  const int*   mask   = (const int*)d_in[2];
  const float* startT = (const float*)d_in[3];
  const float* endT   = (const float*)d_in[4];
  const float* trans  = (const float*)d_in[5];

  float* ws      = (float*)d_ws;
  float* pbuf    = ws;                       // 256*128
  float* qbuf    = ws + 32768;               // 256*128
  float* meta    = ws + 65536;               // 256*4
  float* partial = ws + 66560;               // 256

  crf_llh_kernel<<<64, 512, 0, stream>>>(emis, tags, mask, startT, endT,
                                         trans, pbuf, qbuf, meta);
  crf_meet<<<Bc, 64, 0, stream>>>(pbuf, qbuf, meta, partial);
  crf_reduce<<<1, Bc, 0, stream>>>(partial, (float*)d_out);
}

// Round 15
// 131.647 us; speedup vs baseline: 1.6739x; 1.6739x over previous
//
#include <hip/hip_runtime.h>

static constexpr int Lc = 512;
static constexpr int Bc = 256;
static constexpr int Tc = 128;

typedef _Float16 half2_t  __attribute__((ext_vector_type(2)));
typedef __fp16   fp16x2_t __attribute__((ext_vector_type(2)));

__device__ __forceinline__ float fdot2(half2_t a, half2_t b, float c) {
  return __builtin_amdgcn_fdot2(a, b, c, false);   // v_dot2_f32_f16
}
__device__ __forceinline__ unsigned pack_h2(float a, float b) {
  union { fp16x2_t h; unsigned u; } cv;
  cv.h = __builtin_amdgcn_cvt_pkrtz(a, b);         // v_cvt_pkrtz_f16_f32
  return cv.u;
}
__device__ __forceinline__ half2_t as_h2(unsigned u) {
  union { unsigned u; half2_t h; } cv;
  cv.u = u;
  return cv.h;
}
// quad_perm [1,0,3,2]: combine the two i-halves (lane pairs).
__device__ __forceinline__ float pair_add(float x) {
  const int y = __builtin_amdgcn_update_dpp(0, __float_as_int(x), 0xB1, 0xf, 0xf, true);
  return x + __int_as_float(y);
}
// quad_perm [2,3,0,1]: lane 4m fetches lane 4m+2's value.
__device__ __forceinline__ float quad_fetch2(float x) {
  const int y = __builtin_amdgcn_update_dpp(0, __float_as_int(x), 0x4E, 0xf, 0xf, true);
  return __int_as_float(y);
}

// Meet-in-the-middle with BOTH chains in ONE block: 256 blocks x 512 thr
// (1 block/CU -- kills R13's 2-block/CU barrier interference). Waves 0-3 =
// forward chain (R12's proven f16-dot2 GEMV shape), waves 4-7 = backward
// (transposed) chain of the SAME batch. One lgkmcnt-only barrier per
// iteration serves both chains. fwd: 256 steps -> p_256; bwd: 255 steps ->
// q_256 (idles iteration 256, still hits the barrier); denom = q.p.
__launch_bounds__(512, 1)
__global__ void crf_llh_kernel(const float* __restrict__ emis,
                               const int* __restrict__ tags,
                               const int* __restrict__ mask,
                               const float* __restrict__ startT,
                               const float* __restrict__ endT,
                               const float* __restrict__ trans,
                               float* __restrict__ pbuf,    // [256][128]
                               float* __restrict__ qbuf,    // [256][128]
                               float* __restrict__ meta)    // [256][4]
{
  const int b    = blockIdx.x;
  const int tid  = threadIdx.x;
  const int grp  = tid >> 8;           // 0 = fwd, 1 = bwd
  const int ltid = tid & 255;
  const int jj   = ltid >> 1;          // fwd: out col j; bwd: out row i
  const int h    = ltid & 1;           // half of the 128-reduction
  const int wid  = tid >> 6;           // wave 0..7
  const int lane = tid & 63;

  __shared__ __align__(16) unsigned p_lds[2][2][64];  // [buf][grp][slot]
  __shared__ int expo_lds[2][2];                      // [buf][grp]
  __shared__ float wredA[4];
  __shared__ float wredB[4];
  __shared__ float wredM[4];

  const size_t strideT = (size_t)Bc * Tc;
  const float* emp = emis + (size_t)b * Tc + jj;

  // ---------------- prologue ----------------
  float score = 0.f;   // tid 0 only
  if (grp == 0) {
    // numerator (gold-path score): 256 threads x 2 timesteps
    float v = 0.f, c = 0.f;
    #pragma unroll
    for (int s2 = 0; s2 < 2; ++s2) {
      const int t     = ltid + s2 * 256;
      const float mf  = (float)mask[t * Bc + b];
      const int tag_t = tags[t * Bc + b];
      float e = emis[((size_t)t * Bc + b) * Tc + tag_t] * mf;
      if (t >= 1) e += trans[tags[(t - 1) * Bc + b] * Tc + tag_t] * mf;
      v += e; c += mf;
    }
    #pragma unroll
    for (int o = 1; o < 64; o <<= 1) {
      v += __shfl_xor(v, o);
      c += __shfl_xor(c, o);
    }
    if (lane == 0) { wredA[wid] = v; wredB[wid] = c; }
  }
  __syncthreads();   // #1
  if (tid == 0) {
    const float sv = (wredA[0] + wredA[1]) + (wredA[2] + wredA[3]);
    const float sc = (wredB[0] + wredB[1]) + (wredB[2] + wredB[3]);
    const int last_idx = (int)(sc + 0.5f) - 1;
    score = sv + startT[tags[b]] + endT[tags[last_idx * Bc + b]];
  }

  // E slice: 32 packed f16x2 words (the allocator-safe array size).
  unsigned Eu[32];
  float lp0 = 0.f;
  if (grp == 0) {
    // fwd: column slice, packed along i: Eu[q] = (E[h*64+2q][jj], E[h*64+2q+1][jj])
    #pragma unroll
    for (int q = 0; q < 32; ++q) {
      const float e0 = __expf(trans[(h * 64 + 2 * q)     * Tc + jj]);
      const float e1 = __expf(trans[(h * 64 + 2 * q + 1) * Tc + jj]);
      Eu[q] = pack_h2(e0, e1);
    }
    lp0 = startT[jj] + emp[0];
    float wm = lp0;
    #pragma unroll
    for (int o = 1; o < 64; o <<= 1) wm = fmaxf(wm, __shfl_xor(wm, o));
    if (lane == 0) wredM[wid] = wm;   // wid 0..3
  } else {
    // bwd: row slice, packed along j: Eu[q] = (E[jj][h*64+2q], E[jj][h*64+2q+1])
    #pragma unroll
    for (int q = 0; q < 32; ++q) {
      const float2 tr2 = *(const float2*)&trans[jj * Tc + h * 64 + 2 * q];
      Eu[q] = pack_h2(__expf(tr2.x), __expf(tr2.y));
    }
  }
  __syncthreads();   // #2

  // chain state + init writes
  float st = 0.f;    // fwd: p_t[jj]; bwd: q_t[jj]
  float M0 = 0.f;
  if (grp == 0) {
    M0 = fmaxf(fmaxf(wredM[0], wredM[1]), fmaxf(wredM[2], wredM[3]));
    st = __expf(lp0 - M0);
    const float partner = quad_fetch2(st);
    if ((ltid & 3) == 0) p_lds[0][0][ltid >> 2] = pack_h2(st, partner);
    if (ltid == 0) expo_lds[0][0] = 0;
  } else {
    st = __expf(endT[jj]);            // q_511
    const float u = st * __expf(emp[511 * strideT]);
    const float partner = quad_fetch2(u);
    if ((ltid & 3) == 0) p_lds[0][1][ltid >> 2] = pack_h2(u, partner);
    if (ltid == 0) expo_lds[0][1] = 0;
  }

  // prefetch streams, 3 deep
  float emR0, emR1, emR2;
  int   mR0,  mR1,  mR2;
  const float* emP;
  const int*   mP;
  if (grp == 0) {   // consume em[t], mask[t] at t = 1,2,3,...
    emR0 = emp[1 * strideT]; emR1 = emp[2 * strideT]; emR2 = emp[3 * strideT];
    mR0  = mask[1 * Bc + b]; mR1  = mask[2 * Bc + b]; mR2  = mask[3 * Bc + b];
    emP  = emp + 4 * strideT;          // em[k+3], k = 1..256 -> max em[259]
    mP   = mask + 4 * Bc + b;
  } else {          // consume mask[t], em[t-1] at t = 511,510,...
    mR0  = mask[511 * Bc + b]; mR1 = mask[510 * Bc + b]; mR2 = mask[509 * Bc + b];
    emR0 = emp[510 * strideT]; emR1 = emp[509 * strideT]; emR2 = emp[508 * strideT];
    emP  = emp + 507 * strideT;        // em[508-k] >= em[253]
    mP   = mask + 508 * Bc + b;        // m[509-k]  >= m[254]
  }
  __syncthreads();   // #3

  // ---------------- fused recurrence: one barrier serves both chains ------
  int Ks = 0, buf = 0;
  for (int k = 1; k <= 256; ++k) {
    if (grp == 0 || k <= 255) {
      const int e0 = expo_lds[buf][grp];
      const uint4* pv = (const uint4*)&p_lds[buf][grp][h * 32];
      float a0 = 0.f, a1 = 0.f, a2 = 0.f, a3 = 0.f;
      float a4 = 0.f, a5 = 0.f, a6 = 0.f, a7 = 0.f;
      #pragma unroll
      for (int q = 0; q < 8; ++q) {
        const uint4 pq = pv[q];
        if (q & 1) {
          a4 = fdot2(as_h2(pq.x), as_h2(Eu[q * 4 + 0]), a4);
          a5 = fdot2(as_h2(pq.y), as_h2(Eu[q * 4 + 1]), a5);
          a6 = fdot2(as_h2(pq.z), as_h2(Eu[q * 4 + 2]), a6);
          a7 = fdot2(as_h2(pq.w), as_h2(Eu[q * 4 + 3]), a7);
        } else {
          a0 = fdot2(as_h2(pq.x), as_h2(Eu[q * 4 + 0]), a0);
          a1 = fdot2(as_h2(pq.y), as_h2(Eu[q * 4 + 1]), a1);
          a2 = fdot2(as_h2(pq.z), as_h2(Eu[q * 4 + 2]), a2);
          a3 = fdot2(as_h2(pq.w), as_h2(Eu[q * 4 + 3]), a3);
        }
      }
      float s = ((a0 + a1) + (a2 + a3)) + ((a4 + a5) + (a6 + a7));
      s = pair_add(s);

      // prefetch (always in-bounds for both groups)
      const float emNew = emP[0];
      const int   mNew  = mP[0];
      if (grp == 0) { emP += strideT; mP += Bc; }
      else          { emP -= strideT; mP -= Bc; }

      const float r = __uint_as_float((unsigned)(127 - e0) << 23);  // 2^-e0
      float pn;
      if (grp == 0) {
        pn = (mR0 ? s * __expf(emR0) : st) * r;   // p_t
      } else {
        pn = (mR0 ? s : st) * r;                  // q_{t-1}
      }
      Ks += e0;
      st = pn;

      const int nxt = buf ^ 1;
      // write next broadcast vector: fwd writes p_t; bwd writes u_{t-1}
      const float wv = (grp == 0) ? pn : pn * __expf(emR0);
      const float partner = quad_fetch2(wv);
      if ((ltid & 3) == 0) p_lds[nxt][grp][ltid >> 2] = pack_h2(wv, partner);
      if (ltid == 0) {
        int e = (int)((__float_as_uint(pn) >> 23) & 0xff) - 127;
        expo_lds[nxt][grp] = min(max(e, -100), 100);
      }

      emR0 = emR1; emR1 = emR2; emR2 = emNew;
      mR0  = mR1;  mR1  = mR2;  mR2  = mNew;
    }

    asm volatile("s_waitcnt lgkmcnt(0)" ::: "memory");
    __builtin_amdgcn_s_barrier();
    asm volatile("" ::: "memory");
    buf ^= 1;
  }

  // ---------------- outputs ----------------
  if (grp == 0) {
    if (h == 0) pbuf[b * Tc + jj] = st;           // p_256
    if (tid == 0) {
      meta[4 * b + 0] = score;
      meta[4 * b + 1] = M0;
      meta[4 * b + 2] = (float)Ks;
    }
  } else {
    if (h == 0) qbuf[b * Tc + jj] = st;           // q_256
    if (ltid == 0) meta[4 * b + 3] = (float)Ks;
  }
}

// Meet: denom_b = M0 + (Kf+Kb)*ln2 + log(p_256 . q_256); partial = score - denom.
__global__ void crf_meet(const float* __restrict__ pbuf,
                         const float* __restrict__ qbuf,
                         const float* __restrict__ meta,
                         float* __restrict__ partial)
{
  const int b = blockIdx.x;
  const int l = threadIdx.x;   // 64
  const float2 pp = *(const float2*)&pbuf[b * Tc + 2 * l];
  const float2 qq = *(const float2*)&qbuf[b * Tc + 2 * l];
  float d = pp.x * qq.x + pp.y * qq.y;
  #pragma unroll
  for (int o = 1; o < 64; o <<= 1) d += __shfl_xor(d, o);
  if (l == 0) {
    const float score = meta[4 * b + 0];
    const float M0    = meta[4 * b + 1];
    const float Ks    = meta[4 * b + 2] + meta[4 * b + 3];
    partial[b] = score - (M0 + Ks * 0.69314718055994531f + __logf(d));
  }
}

// Deterministic final reduction of 256 per-batch llh values -> scalar.
__global__ void crf_reduce(const float* __restrict__ partial, float* __restrict__ out)
{
  const int tid = threadIdx.x;  // 256 threads
  float v = partial[tid];
  #pragma unroll
  for (int o = 1; o < 64; o <<= 1) v += __shfl_xor(v, o);
  __shared__ float ws[4];
  if ((tid & 63) == 0) ws[tid >> 6] = v;
  __syncthreads();
  if (tid == 0) out[0] = (ws[0] + ws[1]) + (ws[2] + ws[3]);
}

extern "C" void kernel_launch(void* const* d_in, const int* in_sizes, int n_in,
                              void* d_out, int out_size, void* d_ws, size_t ws_size,
                              hipStream_t stream)
{
  const float* emis   = (const float*)d_in[0];
  const int*   tags   = (const int*)d_in[1];
  const int*   mask   = (const int*)d_in[2];
  const float* startT = (const float*)d_in[3];
  const float* endT   = (const float*)d_in[4];
  const float* trans  = (const float*)d_in[5];

  float* ws      = (float*)d_ws;
  float* pbuf    = ws;                       // 256*128
  float* qbuf    = ws + 32768;               // 256*128
  float* meta    = ws + 65536;               // 256*4
  float* partial = ws + 66560;               // 256

  crf_llh_kernel<<<Bc, 512, 0, stream>>>(emis, tags, mask, startT, endT,
                                         trans, pbuf, qbuf, meta);
  crf_meet<<<Bc, 64, 0, stream>>>(pbuf, qbuf, meta, partial);
  crf_reduce<<<1, Bc, 0, stream>>>(partial, (float*)d_out);
}

// Round 16
// 129.480 us; speedup vs baseline: 1.7019x; 1.0167x over previous
//
#include <hip/hip_runtime.h>

static constexpr int Lc = 512;
static constexpr int Bc = 256;
static constexpr int Tc = 128;

typedef _Float16 half2_t  __attribute__((ext_vector_type(2)));
typedef __fp16   fp16x2_t __attribute__((ext_vector_type(2)));

__device__ __forceinline__ float fdot2(half2_t a, half2_t b, float c) {
  return __builtin_amdgcn_fdot2(a, b, c, false);   // v_dot2_f32_f16
}
__device__ __forceinline__ unsigned pack_h2(float a, float b) {
  union { fp16x2_t h; unsigned u; } cv;
  cv.h = __builtin_amdgcn_cvt_pkrtz(a, b);         // v_cvt_pkrtz_f16_f32
  return cv.u;
}
__device__ __forceinline__ half2_t as_h2(unsigned u) {
  union { unsigned u; half2_t h; } cv;
  cv.u = u;
  return cv.h;
}
// quad_perm [1,0,3,2]: combine the two i-halves (lane pairs).
__device__ __forceinline__ float pair_add(float x) {
  const int y = __builtin_amdgcn_update_dpp(0, __float_as_int(x), 0xB1, 0xf, 0xf, true);
  return x + __int_as_float(y);
}
// quad_perm [2,3,0,1]: lane 4m fetches lane 4m+2's value.
__device__ __forceinline__ float quad_fetch2(float x) {
  const int y = __builtin_amdgcn_update_dpp(0, __float_as_int(x), 0x4E, 0xf, 0xf, true);
  return __int_as_float(y);
}

// Fused meet-in-the-middle, BRANCH-FREE main loop (R15 retry).
// R15 lesson: initializing Eu[32] inside divergent if(grp) branches sent it
// to AGPRs (VGPR=48, ~64 accvgpr-copies/step). Fix: all fwd/bwd asymmetry is
// DATA (base/stride/select operands), never control flow. Waves 0-3 = fwd
// chain, waves 4-7 = bwd (transposed) chain of the same batch; one
// lgkmcnt-only barrier per step serves both. Loop runs k=1..255 uniformly;
// fwd's 256th step is hoisted after the loop (last barrier orders it).
__launch_bounds__(512, 1)
__global__ void crf_llh_kernel(const float* __restrict__ emis,
                               const int* __restrict__ tags,
                               const int* __restrict__ mask,
                               const float* __restrict__ startT,
                               const float* __restrict__ endT,
                               const float* __restrict__ trans,
                               float* __restrict__ pbuf,    // [256][128]
                               float* __restrict__ qbuf,    // [256][128]
                               float* __restrict__ meta)    // [256][4]
{
  const int b    = blockIdx.x;
  const int tid  = threadIdx.x;
  const int grp  = tid >> 8;           // 0 = fwd, 1 = bwd
  const int ltid = tid & 255;
  const int jj   = ltid >> 1;          // fwd: out col j; bwd: out row i
  const int h    = ltid & 1;           // half of the 128-reduction
  const int wid  = tid >> 6;           // wave 0..7
  const int lane = tid & 63;

  __shared__ __align__(16) unsigned p_lds[2][2][64];  // [buf][grp][slot]
  __shared__ int expo_lds[2][2];                      // [buf][grp]
  __shared__ float wredA[4];
  __shared__ float wredB[4];
  __shared__ float wredM[4];

  const size_t strideT = (size_t)Bc * Tc;
  const float* emp = emis + (size_t)b * Tc + jj;

  // ---------------- E slice: branch-free init, 32 packed f16x2 ----------
  // fwd (grp=0): Eu[q] = (E[h*64+2q][jj],   E[h*64+2q+1][jj])
  // bwd (grp=1): Eu[q] = (E[jj][h*64+2q],   E[jj][h*64+2q+1])
  const int eBase   = grp ? (jj * Tc + h * 64) : ((h * 64) * Tc + jj);
  const int eStride = grp ? 2 : 2 * Tc;
  const int eOff    = grp ? 1 : Tc;
  unsigned Eu[32];
  #pragma unroll
  for (int q = 0; q < 32; ++q) {
    const float e0v = __expf(trans[eBase + q * eStride]);
    const float e1v = __expf(trans[eBase + q * eStride + eOff]);
    Eu[q] = pack_h2(e0v, e1v);
  }

  // ---------------- prologue (divergent is fine here, one-time) ----------
  float score = 0.f;   // tid 0 only
  if (grp == 0) {
    float v = 0.f, c = 0.f;
    #pragma unroll
    for (int s2 = 0; s2 < 2; ++s2) {
      const int t     = ltid + s2 * 256;
      const float mf  = (float)mask[t * Bc + b];
      const int tag_t = tags[t * Bc + b];
      float e = emis[((size_t)t * Bc + b) * Tc + tag_t] * mf;
      if (t >= 1) e += trans[tags[(t - 1) * Bc + b] * Tc + tag_t] * mf;
      v += e; c += mf;
    }
    #pragma unroll
    for (int o = 1; o < 64; o <<= 1) {
      v += __shfl_xor(v, o);
      c += __shfl_xor(c, o);
    }
    if (lane == 0) { wredA[wid] = v; wredB[wid] = c; }
  }
  __syncthreads();
  if (tid == 0) {
    const float sv = (wredA[0] + wredA[1]) + (wredA[2] + wredA[3]);
    const float sc = (wredB[0] + wredB[1]) + (wredB[2] + wredB[3]);
    const int last_idx = (int)(sc + 0.5f) - 1;
    score = sv + startT[tags[b]] + endT[tags[last_idx * Bc + b]];
  }

  float lp0 = 0.f;
  if (grp == 0) {
    lp0 = startT[jj] + emp[0];
    float wm = lp0;
    #pragma unroll
    for (int o = 1; o < 64; o <<= 1) wm = fmaxf(wm, __shfl_xor(wm, o));
    if (lane == 0) wredM[wid] = wm;   // wid 0..3
  }
  __syncthreads();

  float st, M0 = 0.f;
  if (grp == 0) {
    M0 = fmaxf(fmaxf(wredM[0], wredM[1]), fmaxf(wredM[2], wredM[3]));
    st = __expf(lp0 - M0);
    const float partner = quad_fetch2(st);
    if ((ltid & 3) == 0) p_lds[0][0][ltid >> 2] = pack_h2(st, partner);
    if (ltid == 0) expo_lds[0][0] = 0;
  } else {
    st = __expf(endT[jj]);            // q_511
    const float u = st * __expf(emp[511 * strideT]);
    const float partner = quad_fetch2(u);
    if ((ltid & 3) == 0) p_lds[0][1][ltid >> 2] = pack_h2(u, partner);
    if (ltid == 0) expo_lds[0][1] = 0;
  }

  // prefetch streams, 3 deep; direction is DATA (signed strides)
  const long sT = grp ? -(long)strideT : (long)strideT;
  const int  sB = grp ? -Bc : Bc;
  float emR0, emR1, emR2;
  int   mR0,  mR1,  mR2;
  const float* emP;
  const int*   mP;
  if (grp == 0) {   // consume em[t], mask[t] at t = 1,2,3,...
    emR0 = emp[1 * strideT]; emR1 = emp[2 * strideT]; emR2 = emp[3 * strideT];
    mR0  = mask[1 * Bc + b]; mR1  = mask[2 * Bc + b]; mR2  = mask[3 * Bc + b];
    emP  = emp + 4 * strideT;
    mP   = mask + 4 * Bc + b;
  } else {          // consume mask[512-k], em[511-k] at k = 1,2,...
    mR0  = mask[511 * Bc + b]; mR1 = mask[510 * Bc + b]; mR2 = mask[509 * Bc + b];
    emR0 = emp[510 * strideT]; emR1 = emp[509 * strideT]; emR2 = emp[508 * strideT];
    emP  = emp + 507 * strideT;
    mP   = mask + 508 * Bc + b;
  }
  __syncthreads();

  // ---------------- branch-free fused recurrence, k = 1..255 ----------
  const float one = 1.0f;
  int Ks = 0, buf = 0;
  for (int k = 1; k <= 255; ++k) {
    const int e0 = expo_lds[buf][grp];
    const uint4* pv = (const uint4*)&p_lds[buf][grp][h * 32];
    float a0 = 0.f, a1 = 0.f, a2 = 0.f, a3 = 0.f;
    float a4 = 0.f, a5 = 0.f, a6 = 0.f, a7 = 0.f;
    #pragma unroll
    for (int q = 0; q < 8; ++q) {
      const uint4 pq = pv[q];
      if (q & 1) {
        a4 = fdot2(as_h2(pq.x), as_h2(Eu[q * 4 + 0]), a4);
        a5 = fdot2(as_h2(pq.y), as_h2(Eu[q * 4 + 1]), a5);
        a6 = fdot2(as_h2(pq.z), as_h2(Eu[q * 4 + 2]), a6);
        a7 = fdot2(as_h2(pq.w), as_h2(Eu[q * 4 + 3]), a7);
      } else {
        a0 = fdot2(as_h2(pq.x), as_h2(Eu[q * 4 + 0]), a0);
        a1 = fdot2(as_h2(pq.y), as_h2(Eu[q * 4 + 1]), a1);
        a2 = fdot2(as_h2(pq.z), as_h2(Eu[q * 4 + 2]), a2);
        a3 = fdot2(as_h2(pq.w), as_h2(Eu[q * 4 + 3]), a3);
      }
    }
    float s = ((a0 + a1) + (a2 + a3)) + ((a4 + a5) + (a6 + a7));
    s = pair_add(s);

    const float eEm = __expf(emR0);
    const float eIn  = grp ? one : eEm;   // cndmask, no CFG
    const float eOut = grp ? eEm : one;

    const float emNew = emP[0];
    const int   mNew  = mP[0];
    emP += sT; mP += sB;

    const float r  = __uint_as_float((unsigned)(127 - e0) << 23);  // 2^-e0
    const float pn = (mR0 ? s * eIn : st) * r;
    Ks += e0;
    st = pn;

    const int nxt = buf ^ 1;
    const float wv = pn * eOut;
    const float partner = quad_fetch2(wv);
    if ((ltid & 3) == 0) p_lds[nxt][grp][ltid >> 2] = pack_h2(wv, partner);
    if (ltid == 0) {
      int e = (int)((__float_as_uint(pn) >> 23) & 0xff) - 127;
      expo_lds[nxt][grp] = min(max(e, -100), 100);
    }

    emR0 = emR1; emR1 = emR2; emR2 = emNew;
    mR0  = mR1;  mR1  = mR2;  mR2  = mNew;

    asm volatile("s_waitcnt lgkmcnt(0)" ::: "memory");
    __builtin_amdgcn_s_barrier();
    asm volatile("" ::: "memory");
    buf ^= 1;
  }

  // ---------------- fwd-only step 256 (ordered by the last barrier) -------
  if (grp == 0) {
    const int e0 = expo_lds[buf][0];
    const uint4* pv = (const uint4*)&p_lds[buf][0][h * 32];
    float a0 = 0.f, a1 = 0.f, a2 = 0.f, a3 = 0.f;
    float a4 = 0.f, a5 = 0.f, a6 = 0.f, a7 = 0.f;
    #pragma unroll
    for (int q = 0; q < 8; ++q) {
      const uint4 pq = pv[q];
      if (q & 1) {
        a4 = fdot2(as_h2(pq.x), as_h2(Eu[q * 4 + 0]), a4);
        a5 = fdot2(as_h2(pq.y), as_h2(Eu[q * 4 + 1]), a5);
        a6 = fdot2(as_h2(pq.z), as_h2(Eu[q * 4 + 2]), a6);
        a7 = fdot2(as_h2(pq.w), as_h2(Eu[q * 4 + 3]), a7);
      } else {
        a0 = fdot2(as_h2(pq.x), as_h2(Eu[q * 4 + 0]), a0);
        a1 = fdot2(as_h2(pq.y), as_h2(Eu[q * 4 + 1]), a1);
        a2 = fdot2(as_h2(pq.z), as_h2(Eu[q * 4 + 2]), a2);
        a3 = fdot2(as_h2(pq.w), as_h2(Eu[q * 4 + 3]), a3);
      }
    }
    float s = ((a0 + a1) + (a2 + a3)) + ((a4 + a5) + (a6 + a7));
    s = pair_add(s);

    const float eEm = __expf(emR0);
    const float r   = __uint_as_float((unsigned)(127 - e0) << 23);
    const float pn  = (mR0 ? s * eEm : st) * r;
    Ks += e0;
    st = pn;                           // p_256

    if (h == 0) pbuf[b * Tc + jj] = st;
    if (tid == 0) {
      meta[4 * b + 0] = score;
      meta[4 * b + 1] = M0;
      meta[4 * b + 2] = (float)Ks;
    }
  } else {
    if (h == 0) qbuf[b * Tc + jj] = st;   // q_256
    if (ltid == 0) meta[4 * b + 3] = (float)Ks;
  }
}

// Meet: denom_b = M0 + (Kf+Kb)*ln2 + log(p_256 . q_256); partial = score - denom.
__global__ void crf_meet(const float* __restrict__ pbuf,
                         const float* __restrict__ qbuf,
                         const float* __restrict__ meta,
                         float* __restrict__ partial)
{
  const int b = blockIdx.x;
  const int l = threadIdx.x;   // 64
  const float2 pp = *(const float2*)&pbuf[b * Tc + 2 * l];
  const float2 qq = *(const float2*)&qbuf[b * Tc + 2 * l];
  float d = pp.x * qq.x + pp.y * qq.y;
  #pragma unroll
  for (int o = 1; o < 64; o <<= 1) d += __shfl_xor(d, o);
  if (l == 0) {
    const float score = meta[4 * b + 0];
    const float M0    = meta[4 * b + 1];
    const float Ks    = meta[4 * b + 2] + meta[4 * b + 3];
    partial[b] = score - (M0 + Ks * 0.69314718055994531f + __logf(d));
  }
}

// Deterministic final reduction of 256 per-batch llh values -> scalar.
__global__ void crf_reduce(const float* __restrict__ partial, float* __restrict__ out)
{
  const int tid = threadIdx.x;  // 256 threads
  float v = partial[tid];
  #pragma unroll
  for (int o = 1; o < 64; o <<= 1) v += __shfl_xor(v, o);
  __shared__ float ws[4];
  if ((tid & 63) == 0) ws[tid >> 6] = v;
  __syncthreads();
  if (tid == 0) out[0] = (ws[0] + ws[1]) + (ws[2] + ws[3]);
}

extern "C" void kernel_launch(void* const* d_in, const int* in_sizes, int n_in,
                              void* d_out, int out_size, void* d_ws, size_t ws_size,
                              hipStream_t stream)
{
  const float* emis   = (const float*)d_in[0];
  const int*   tags   = (const int*)d_in[1];
  const int*   mask   = (const int*)d_in[2];
  const float* startT = (const float*)d_in[3];
  const float* endT   = (const float*)d_in[4];
  const float* trans  = (const float*)d_in[5];

  float* ws      = (float*)d_ws;
  float* pbuf    = ws;                       // 256*128
  float* qbuf    = ws + 32768;               // 256*128
  float* meta    = ws + 65536;               // 256*4
  float* partial = ws + 66560;               // 256

  crf_llh_kernel<<<Bc, 512, 0, stream>>>(emis, tags, mask, startT, endT,
                                         trans, pbuf, qbuf, meta);
  crf_meet<<<Bc, 64, 0, stream>>>(pbuf, qbuf, meta, partial);
  crf_reduce<<<1, Bc, 0, stream>>>(partial, (float*)d_out);
}

// Round 17
// 126.077 us; speedup vs baseline: 1.7478x; 1.0270x over previous
//
#include <hip/hip_runtime.h>

static constexpr int Lc = 512;
static constexpr int Bc = 256;
static constexpr int Tc = 128;

typedef _Float16 half2_t  __attribute__((ext_vector_type(2)));
typedef __fp16   fp16x2_t __attribute__((ext_vector_type(2)));

__device__ __forceinline__ float fdot2(half2_t a, half2_t b, float c) {
  return __builtin_amdgcn_fdot2(a, b, c, false);   // v_dot2_f32_f16
}
__device__ __forceinline__ unsigned pack_h2(float a, float b) {
  union { fp16x2_t h; unsigned u; } cv;
  cv.h = __builtin_amdgcn_cvt_pkrtz(a, b);         // v_cvt_pkrtz_f16_f32
  return cv.u;
}
__device__ __forceinline__ half2_t as_h2(unsigned u) {
  union { unsigned u; half2_t h; } cv;
  cv.u = u;
  return cv.h;
}
// quad_perm [1,0,3,2]: combine the two i-halves (lane pairs).
__device__ __forceinline__ float pair_add(float x) {
  const int y = __builtin_amdgcn_update_dpp(0, __float_as_int(x), 0xB1, 0xf, 0xf, true);
  return x + __int_as_float(y);
}
// quad_perm [2,3,0,1]: lane 4m fetches lane 4m+2's value.
__device__ __forceinline__ float quad_fetch2(float x) {
  const int y = __builtin_amdgcn_update_dpp(0, __float_as_int(x), 0x4E, 0xf, 0xf, true);
  return __int_as_float(y);
}

// R13 structure (proven 122us): meet-in-the-middle, fwd chain (blocks 0..255)
// and bwd chain (blocks 256..511) as SEPARATE 256-thread blocks -- the only
// config where the allocator keeps the 32-word E-slice in VGPRs (R12/R13:
// VGPR 80-84; every 512-thr variant went AGPR).
// R17 deltas: score-gather moved to the meet kernel (off the sequential wall
// path); prefetch depth 3->2; s_setprio(1) around compute so working waves
// beat the co-resident block's barrier-waiters at issue arbitration.
__launch_bounds__(256, 1)
__global__ void crf_chain(const float* __restrict__ emis,
                          const int* __restrict__ mask,
                          const float* __restrict__ startT,
                          const float* __restrict__ endT,
                          const float* __restrict__ trans,
                          float* __restrict__ pbuf,    // [256][128]
                          float* __restrict__ qbuf,    // [256][128]
                          float* __restrict__ meta)    // [256][4] _,M0,Kf,Kb
{
  const int bid  = blockIdx.x;
  const bool fwd = bid < Bc;
  const int b    = fwd ? bid : bid - Bc;
  const int tid  = threadIdx.x;
  const int jj   = tid >> 1;   // fwd: out col j; bwd: out row i
  const int h    = tid & 1;    // half of the 128-reduction
  const int wid  = tid >> 6;
  const int lane = tid & 63;

  __shared__ __align__(16) unsigned p_lds[2][64];   // packed f16x2
  __shared__ int expo_lds[2];
  __shared__ float wredM[4];

  const size_t strideT = (size_t)Bc * Tc;
  const float* emp = emis + (size_t)b * Tc + jj;

  if (fwd) {
    // E column-slice, packed along i: Eu[q] = (E[h*64+2q][jj], E[h*64+2q+1][jj])
    unsigned Eu[32];
    #pragma unroll
    for (int q = 0; q < 32; ++q) {
      const float e0 = __expf(trans[(h * 64 + 2 * q)     * Tc + jj]);
      const float e1 = __expf(trans[(h * 64 + 2 * q + 1) * Tc + jj]);
      Eu[q] = pack_h2(e0, e1);
    }

    // init t = 0
    const float lp0 = startT[jj] + emp[0];
    float wm = lp0;
    #pragma unroll
    for (int o = 1; o < 64; o <<= 1) wm = fmaxf(wm, __shfl_xor(wm, o));
    if (lane == 0) wredM[wid] = wm;
    __syncthreads();
    const float M0 = fmaxf(fmaxf(wredM[0], wredM[1]), fmaxf(wredM[2], wredM[3]));

    float st = __expf(lp0 - M0);
    {
      const float partner = quad_fetch2(st);
      if ((tid & 3) == 0) p_lds[0][tid >> 2] = pack_h2(st, partner);
      if (tid == 0) expo_lds[0] = 0;
    }

    // em/mask prefetch, depth 2
    float emR0 = emp[1 * strideT], emR1 = emp[2 * strideT];
    int   mR0  = mask[1 * Bc + b], mR1 = mask[2 * Bc + b];
    const float* emP = emp + 3 * strideT;   // em[t+2], t=1.. -> max em[257]
    const int*   mP  = mask + 3 * Bc + b;
    __syncthreads();

    int Ks = 0, buf = 0;
    #pragma unroll 2
    for (int t = 1; t <= 255; ++t) {
      __builtin_amdgcn_s_setprio(1);
      const int e0 = expo_lds[buf];
      const uint4* pv = (const uint4*)&p_lds[buf][h * 32];
      float a0 = 0.f, a1 = 0.f, a2 = 0.f, a3 = 0.f;
      float a4 = 0.f, a5 = 0.f, a6 = 0.f, a7 = 0.f;
      #pragma unroll
      for (int q = 0; q < 8; ++q) {
        const uint4 pq = pv[q];
        if (q & 1) {
          a4 = fdot2(as_h2(pq.x), as_h2(Eu[q * 4 + 0]), a4);
          a5 = fdot2(as_h2(pq.y), as_h2(Eu[q * 4 + 1]), a5);
          a6 = fdot2(as_h2(pq.z), as_h2(Eu[q * 4 + 2]), a6);
          a7 = fdot2(as_h2(pq.w), as_h2(Eu[q * 4 + 3]), a7);
        } else {
          a0 = fdot2(as_h2(pq.x), as_h2(Eu[q * 4 + 0]), a0);
          a1 = fdot2(as_h2(pq.y), as_h2(Eu[q * 4 + 1]), a1);
          a2 = fdot2(as_h2(pq.z), as_h2(Eu[q * 4 + 2]), a2);
          a3 = fdot2(as_h2(pq.w), as_h2(Eu[q * 4 + 3]), a3);
        }
      }
      float s = ((a0 + a1) + (a2 + a3)) + ((a4 + a5) + (a6 + a7));
      s = pair_add(s);

      const float eEm = __expf(emR0);
      const float emNew = emP[0];
      const int   mNew  = mP[0];
      emP += strideT; mP += Bc;

      const float r  = __uint_as_float((unsigned)(127 - e0) << 23);  // 2^-e0
      const float pn = (mR0 ? s * eEm : st) * r;
      Ks += e0;
      st = pn;

      const int nxt = buf ^ 1;
      const float partner = quad_fetch2(pn);
      if ((tid & 3) == 0) p_lds[nxt][tid >> 2] = pack_h2(pn, partner);
      if (tid == 0) {
        int e = (int)((__float_as_uint(pn) >> 23) & 0xff) - 127;
        expo_lds[nxt] = min(max(e, -100), 100);
      }
      __builtin_amdgcn_s_setprio(0);

      emR0 = emR1; emR1 = emNew;
      mR0  = mR1;  mR1  = mNew;

      asm volatile("s_waitcnt lgkmcnt(0)" ::: "memory");
      __builtin_amdgcn_s_barrier();
      asm volatile("" ::: "memory");
      buf = nxt;
    }

    if (h == 0) pbuf[b * Tc + jj] = st;            // p_255
    if (tid == 0) {
      meta[4 * b + 1] = M0;
      meta[4 * b + 2] = (float)Ks;
    }
  } else {
    // E row-slice, packed along j: Eu[q] = (E[jj][h*64+2q], E[jj][h*64+2q+1])
    unsigned Eu[32];
    #pragma unroll
    for (int q = 0; q < 32; ++q) {
      const float2 tr2 = *(const float2*)&trans[jj * Tc + h * 64 + 2 * q];
      Eu[q] = pack_h2(__expf(tr2.x), __expf(tr2.y));
    }

    // init: q_511 = exp(end); u_511 = eEm_511 .* q_511
    float st = __expf(endT[jj]);
    {
      const float u = st * __expf(emp[511 * strideT]);
      const float partner = quad_fetch2(u);
      if ((tid & 3) == 0) p_lds[0][tid >> 2] = pack_h2(u, partner);
      if (tid == 0) expo_lds[0] = 0;
    }

    // streams, depth 2: m[511],m[510]; em[510],em[509]
    int   mR0 = mask[511 * Bc + b], mR1 = mask[510 * Bc + b];
    float emR0 = emp[510 * strideT], emR1 = emp[509 * strideT];
    const float* emP = emp + 508 * strideT;   // em[508-k] >= em[253]
    const int*   mP  = mask + 509 * Bc + b;   // m[509-k]  >= m[254]
    __syncthreads();

    int Ks = 0, buf = 0;
    #pragma unroll 2
    for (int k = 0; k < 256; ++k) {            // t = 511 - k
      __builtin_amdgcn_s_setprio(1);
      const int e0 = expo_lds[buf];
      const uint4* pv = (const uint4*)&p_lds[buf][h * 32];
      float a0 = 0.f, a1 = 0.f, a2 = 0.f, a3 = 0.f;
      float a4 = 0.f, a5 = 0.f, a6 = 0.f, a7 = 0.f;
      #pragma unroll
      for (int q = 0; q < 8; ++q) {
        const uint4 pq = pv[q];
        if (q & 1) {
          a4 = fdot2(as_h2(pq.x), as_h2(Eu[q * 4 + 0]), a4);
          a5 = fdot2(as_h2(pq.y), as_h2(Eu[q * 4 + 1]), a5);
          a6 = fdot2(as_h2(pq.z), as_h2(Eu[q * 4 + 2]), a6);
          a7 = fdot2(as_h2(pq.w), as_h2(Eu[q * 4 + 3]), a7);
        } else {
          a0 = fdot2(as_h2(pq.x), as_h2(Eu[q * 4 + 0]), a0);
          a1 = fdot2(as_h2(pq.y), as_h2(Eu[q * 4 + 1]), a1);
          a2 = fdot2(as_h2(pq.z), as_h2(Eu[q * 4 + 2]), a2);
          a3 = fdot2(as_h2(pq.w), as_h2(Eu[q * 4 + 3]), a3);
        }
      }
      float s = ((a0 + a1) + (a2 + a3)) + ((a4 + a5) + (a6 + a7));
      s = pair_add(s);

      const float emNew = emP[0];
      const int   mNew  = mP[0];
      emP -= strideT; mP -= Bc;

      const float r  = __uint_as_float((unsigned)(127 - e0) << 23);
      const float pn = (mR0 ? s : st) * r;     // q_{t-1}
      Ks += e0;
      st = pn;

      const int nxt = buf ^ 1;
      const float u = pn * __expf(emR0);       // u_{t-1} = eEm_{t-1} * q_{t-1}
      const float partner = quad_fetch2(u);
      if ((tid & 3) == 0) p_lds[nxt][tid >> 2] = pack_h2(u, partner);
      if (tid == 0) {
        int e = (int)((__float_as_uint(pn) >> 23) & 0xff) - 127;
        expo_lds[nxt] = min(max(e, -100), 100);
      }
      __builtin_amdgcn_s_setprio(0);

      mR0  = mR1;  mR1  = mNew;
      emR0 = emR1; emR1 = emNew;

      asm volatile("s_waitcnt lgkmcnt(0)" ::: "memory");
      __builtin_amdgcn_s_barrier();
      asm volatile("" ::: "memory");
      buf = nxt;
    }

    if (h == 0) qbuf[b * Tc + jj] = st;        // q_255
    if (tid == 0) meta[4 * b + 3] = (float)Ks;
  }
}

// Meet kernel: numerator score (moved off the chain wall path) + p.q dot.
__global__ void crf_meet(const float* __restrict__ emis,
                         const int* __restrict__ tags,
                         const int* __restrict__ mask,
                         const float* __restrict__ startT,
                         const float* __restrict__ endT,
                         const float* __restrict__ trans,
                         const float* __restrict__ pbuf,
                         const float* __restrict__ qbuf,
                         const float* __restrict__ meta,
                         float* __restrict__ partial)
{
  const int b    = blockIdx.x;
  const int tid  = threadIdx.x;   // 256
  const int wid  = tid >> 6;
  const int lane = tid & 63;

  __shared__ float wredA[4];
  __shared__ float wredB[4];

  // gold-path score: 2 timesteps per thread
  float v = 0.f, c = 0.f;
  #pragma unroll
  for (int s2 = 0; s2 < 2; ++s2) {
    const int t     = tid + s2 * 256;
    const float mf  = (float)mask[t * Bc + b];
    const int tag_t = tags[t * Bc + b];
    float e = emis[((size_t)t * Bc + b) * Tc + tag_t] * mf;
    if (t >= 1) e += trans[tags[(t - 1) * Bc + b] * Tc + tag_t] * mf;
    v += e; c += mf;
  }
  #pragma unroll
  for (int o = 1; o < 64; o <<= 1) {
    v += __shfl_xor(v, o);
    c += __shfl_xor(c, o);
  }
  if (lane == 0) { wredA[wid] = v; wredB[wid] = c; }
  __syncthreads();

  if (wid == 0) {
    const float2 pp = *(const float2*)&pbuf[b * Tc + 2 * lane];
    const float2 qq = *(const float2*)&qbuf[b * Tc + 2 * lane];
    float d = pp.x * qq.x + pp.y * qq.y;
    #pragma unroll
    for (int o = 1; o < 64; o <<= 1) d += __shfl_xor(d, o);
    if (lane == 0) {
      const float sv = (wredA[0] + wredA[1]) + (wredA[2] + wredA[3]);
      const float sc = (wredB[0] + wredB[1]) + (wredB[2] + wredB[3]);
      const int last_idx = (int)(sc + 0.5f) - 1;
      const float score = sv + startT[tags[b]] + endT[tags[last_idx * Bc + b]];
      const float M0 = meta[4 * b + 1];
      const float Ks = meta[4 * b + 2] + meta[4 * b + 3];
      partial[b] = score - (M0 + Ks * 0.69314718055994531f + __logf(d));
    }
  }
}

// Deterministic final reduction of 256 per-batch llh values -> scalar.
__global__ void crf_reduce(const float* __restrict__ partial, float* __restrict__ out)
{
  const int tid = threadIdx.x;  // 256 threads
  float v = partial[tid];
  #pragma unroll
  for (int o = 1; o < 64; o <<= 1) v += __shfl_xor(v, o);
  __shared__ float ws[4];
  if ((tid & 63) == 0) ws[tid >> 6] = v;
  __syncthreads();
  if (tid == 0) out[0] = (ws[0] + ws[1]) + (ws[2] + ws[3]);
}

extern "C" void kernel_launch(void* const* d_in, const int* in_sizes, int n_in,
                              void* d_out, int out_size, void* d_ws, size_t ws_size,
                              hipStream_t stream)
{
  const float* emis   = (const float*)d_in[0];
  const int*   tags   = (const int*)d_in[1];
  const int*   mask   = (const int*)d_in[2];
  const float* startT = (const float*)d_in[3];
  const float* endT   = (const float*)d_in[4];
  const float* trans  = (const float*)d_in[5];

  float* ws      = (float*)d_ws;
  float* pbuf    = ws;                       // 256*128
  float* qbuf    = ws + 32768;               // 256*128
  float* meta    = ws + 65536;               // 256*4
  float* partial = ws + 66560;               // 256

  crf_chain<<<2 * Bc, 256, 0, stream>>>(emis, mask, startT, endT, trans,
                                        pbuf, qbuf, meta);
  crf_meet<<<Bc, 256, 0, stream>>>(emis, tags, mask, startT, endT, trans,
                                   pbuf, qbuf, meta, partial);
  crf_reduce<<<1, Bc, 0, stream>>>(partial, (float*)d_out);
}